// Round 7
// baseline (249.232 us; speedup 1.0000x reference)
//
#include <hip/hip_runtime.h>

#define DI __device__ __forceinline__

DI float silu_f(float x) { return x / (1.f + __expf(-x)); }
DI float sigmoid_f(float x) { return 1.f / (1.f + __expf(-x)); }
DI int reflect_i(int i, int n) { if (i < 0) i = -i; if (i >= n) i = 2 * n - 2 - i; return i; }

// K1: bilinear resize (2,3,1024,1024) -> (2,3,256,256), align-corners style.
// Block = one output row: stage the 2 source rows in LDS (coalesced float4),
// gather from LDS. grid = 6 planes * 256 rows.
__global__ __launch_bounds__(256) void k_resize(const float* __restrict__ img,
                                                float* __restrict__ x) {
    __shared__ float r0s[1024], r1s[1024];
    const int oy = blockIdx.x & 255;
    const int bc = blockIdx.x >> 8;  // 0..5
    float py = oy * (1023.f / 255.f);
    int iy0 = (int)py; if (iy0 > 1022) iy0 = 1022;
    float fy = py - (float)iy0;
    const float* p0 = img + ((size_t)bc * 1024 + iy0) * 1024;
    ((float4*)r0s)[threadIdx.x] = ((const float4*)p0)[threadIdx.x];
    ((float4*)r1s)[threadIdx.x] = ((const float4*)(p0 + 1024))[threadIdx.x];
    __syncthreads();
    const int ox = threadIdx.x;
    float px = ox * (1023.f / 255.f);
    int ix0 = (int)px; if (ix0 > 1022) ix0 = 1022;
    float fx = px - (float)ix0;
    float a00 = r0s[ix0], a01 = r0s[ix0 + 1];
    float a10 = r1s[ix0], a11 = r1s[ix0 + 1];
    float r0v = a00 + fy * (a10 - a00);
    float r1v = a01 + fy * (a11 - a01);
    x[((size_t)bc * 256 + oy) * 256 + ox] = r0v + fx * (r1v - r0v);
}

// 3x3 stride-2 reflect conv + SiLU, wave-per-oc-pair (conv1/conv2).
// Block = 4 waves; wave handles 2 ocs over ALL Cin; lane = consecutive out px.
// Input loads lane-stride 2 floats (coalesced-ish); weight reads wave-uniform.
template<int CIN, int HIN, int WIN, int COUT>
__global__ __launch_bounds__(256) void k_conv_woc(const float* __restrict__ in,
                                                  const float* __restrict__ w,
                                                  const float* __restrict__ bias,
                                                  float* __restrict__ out) {
    constexpr int HOUT = HIN / 2, WOUT = WIN / 2;
    constexpr int NPXU = 2 * HOUT * WOUT;
    constexpr int NB_PX = NPXU / 64;

    __shared__ float sw[8 * CIN * 12];
    const int tid = threadIdx.x;
    const int ocu = blockIdx.x / NB_PX;   // oc-octet index
    const int bpx = blockIdx.x % NB_PX;
    {
        const float* src = w + (size_t)(ocu * 8) * CIN * 9;
        for (int i = tid; i < 8 * CIN * 9; i += 256)
            sw[(i / 9) * 12 + (i % 9)] = src[i];
    }
    __syncthreads();

    const int wave = tid >> 6, lane = tid & 63;
    const int pxu = bpx * 64 + lane;
    const int ox = pxu % WOUT;
    const int oy = (pxu / WOUT) % HOUT;
    const int bb = pxu / (WOUT * HOUT);

    int iy[3], xs[3];
#pragma unroll
    for (int k = 0; k < 3; ++k) {
        iy[k] = reflect_i(2 * oy + k - 1, HIN);
        xs[k] = reflect_i(2 * ox + k - 1, WIN);
    }

    float acc[2] = {0.f, 0.f};
    for (int ic = 0; ic < CIN; ++ic) {
        const float* ib = in + ((size_t)bb * CIN + ic) * HIN * WIN;
        float t[3][3];
#pragma unroll
        for (int ky = 0; ky < 3; ++ky) {
            const float* rp = ib + iy[ky] * WIN;
#pragma unroll
            for (int kx = 0; kx < 3; ++kx) t[ky][kx] = rp[xs[kx]];
        }
#pragma unroll
        for (int o = 0; o < 2; ++o) {
            const float* wp = sw + ((size_t)(wave * 2 + o) * CIN + ic) * 12;
            float wv[9];
#pragma unroll
            for (int j = 0; j < 9; ++j) wv[j] = wp[j];
#pragma unroll
            for (int ky = 0; ky < 3; ++ky)
#pragma unroll
                for (int kx = 0; kx < 3; ++kx)
                    acc[o] = fmaf(t[ky][kx], wv[ky * 3 + kx], acc[o]);
        }
    }

#pragma unroll
    for (int o = 0; o < 2; ++o) {
        const int oc = ocu * 8 + wave * 2 + o;
        out[(((size_t)bb * COUT + oc) * HOUT + oy) * WOUT + ox] =
            silu_f(acc[o] + bias[oc]);
    }
}

// 3x3 stride-2 reflect conv + SiLU with wave-level 4-way K-split (conv3/conv4).
template<int CIN, int HIN, int WIN, int COUT, int OC_PER>
__global__ __launch_bounds__(256) void k_conv_w4(const float* __restrict__ in,
                                                 const float* __restrict__ w,
                                                 const float* __restrict__ bias,
                                                 float* __restrict__ out) {
    constexpr int HOUT = HIN / 2, WOUT = WIN / 2;
    constexpr int NPXU = 2 * HOUT * WOUT;
    constexpr int NB_PX = NPXU / 64;
    constexpr int ICC = CIN / 4;

    __shared__ float sw[OC_PER * CIN * 12];
    __shared__ float sred[4][OC_PER][64];
    const int tid = threadIdx.x;
    const int ocu = blockIdx.x / NB_PX;
    const int bpx = blockIdx.x % NB_PX;
    {
        const float* src = w + (size_t)(ocu * OC_PER) * CIN * 9;
        for (int i = tid; i < OC_PER * CIN * 9; i += 256)
            sw[(i / 9) * 12 + (i % 9)] = src[i];
    }
    __syncthreads();

    const int kc = tid >> 6;
    const int lane = tid & 63;
    const int pxu = bpx * 64 + lane;
    const int ox = pxu % WOUT;
    const int oy = (pxu / WOUT) % HOUT;
    const int bb = pxu / (WOUT * HOUT);

    int iy[3], xs[3];
#pragma unroll
    for (int k = 0; k < 3; ++k) {
        iy[k] = reflect_i(2 * oy + k - 1, HIN);
        xs[k] = reflect_i(2 * ox + k - 1, WIN);
    }

    float acc[OC_PER];
#pragma unroll
    for (int o = 0; o < OC_PER; ++o) acc[o] = 0.f;

    for (int icl = 0; icl < ICC; ++icl) {
        const int ic = kc * ICC + icl;
        const float* ib = in + ((size_t)bb * CIN + ic) * HIN * WIN;
        float t[3][3];
#pragma unroll
        for (int ky = 0; ky < 3; ++ky) {
            const float* rp = ib + iy[ky] * WIN;
#pragma unroll
            for (int kx = 0; kx < 3; ++kx) t[ky][kx] = rp[xs[kx]];
        }
#pragma unroll
        for (int o = 0; o < OC_PER; ++o) {
            const float* wp = sw + ((size_t)o * CIN + ic) * 12;
            float wv[9];
#pragma unroll
            for (int j = 0; j < 9; ++j) wv[j] = wp[j];
#pragma unroll
            for (int ky = 0; ky < 3; ++ky)
#pragma unroll
                for (int kx = 0; kx < 3; ++kx)
                    acc[o] = fmaf(t[ky][kx], wv[ky * 3 + kx], acc[o]);
        }
    }

#pragma unroll
    for (int o = 0; o < OC_PER; ++o) sred[kc][o][lane] = acc[o];
    __syncthreads();
    if (kc < OC_PER) {
        const int o = kc;
        const int oc = ocu * OC_PER + o;
        float s = sred[0][o][lane] + sred[1][o][lane] + sred[2][o][lane] + sred[3][o][lane];
        out[(((size_t)bb * COUT + oc) * HOUT + oy) * WOUT + ox] = silu_f(s + bias[oc]);
    }
}

// K6: fused avg-pool + concat -> feat (2,480,8,8), float4 inner reads
__global__ void k_pool(const float* __restrict__ c1, const float* __restrict__ c2,
                       const float* __restrict__ c3, const float* __restrict__ c4,
                       float* __restrict__ feat) {
    int idx = blockIdx.x * blockDim.x + threadIdx.x;
    if (idx >= 2 * 480 * 64) return;
    int x = idx & 7;
    int y = (idx >> 3) & 7;
    int fc = (idx >> 6) % 480;
    int bb = idx / (480 * 64);
    const float* src; int C, HW, k, c;
    if (fc < 32)       { src = c1; C = 32;  HW = 128; k = 16; c = fc; }
    else if (fc < 96)  { src = c2; C = 64;  HW = 64;  k = 8;  c = fc - 32; }
    else if (fc < 224) { src = c3; C = 128; HW = 32;  k = 4;  c = fc - 96; }
    else               { src = c4; C = 256; HW = 16;  k = 2;  c = fc - 224; }
    const float* p = src + ((size_t)bb * C + c) * HW * HW + (y * k) * HW + x * k;
    float s = 0.f;
    if (k >= 4) {
        for (int i = 0; i < k; ++i) {
            const float4* r4 = (const float4*)(p + i * HW);
            for (int j = 0; j < k / 4; ++j) {
                float4 q = r4[j];
                s += q.x + q.y + q.z + q.w;
            }
        }
    } else {
        for (int i = 0; i < k; ++i)
            for (int j = 0; j < k; ++j) s += p[i * HW + j];
    }
    feat[idx] = s / (float)(k * k);
}

// K7: lin1 = 3x3 reflect conv 480->128 on 8x8 + SiLU.
// Block (512 thr = 8 waves) per (bb, oc). Lane = pixel; wave = 1/8 of ic range.
__global__ __launch_bounds__(512) void k_lin1(const float* __restrict__ feat,
                                              const float* __restrict__ w,
                                              const float* __restrict__ bias,
                                              float* __restrict__ h1) {
    __shared__ float sw[480 * 9];
    __shared__ float sred[8][64];
    const int tid = threadIdx.x;
    const int bb = blockIdx.x >> 7;
    const int oc = blockIdx.x & 127;
    {
        const float* src = w + (size_t)oc * 480 * 9;
        for (int i = tid; i < 480 * 9; i += 512) sw[i] = src[i];
    }
    const int wave = tid >> 6;
    const int lane = tid & 63;
    const int py = lane >> 3, px = lane & 7;
    int srcl[9];
#pragma unroll
    for (int ky = 0; ky < 3; ++ky)
#pragma unroll
        for (int kx = 0; kx < 3; ++kx)
            srcl[ky * 3 + kx] = reflect_i(py + ky - 1, 8) * 8 + reflect_i(px + kx - 1, 8);
    __syncthreads();

    const float* fp = feat + (size_t)bb * 480 * 64;
    float acc = 0.f;
    for (int ic = wave * 60; ic < wave * 60 + 60; ++ic) {
        float v = fp[ic * 64 + lane];
        const float* wp = sw + ic * 9;
#pragma unroll
        for (int j = 0; j < 9; ++j)
            acc = fmaf(__shfl(v, srcl[j], 64), wp[j], acc);
    }
    sred[wave][lane] = acc;
    __syncthreads();
    if (wave == 0) {
        float s = 0.f;
#pragma unroll
        for (int wv = 0; wv < 8; ++wv) s += sred[wv][lane];
        h1[((size_t)bb * 128 + oc) * 64 + lane] = silu_f(s + bias[oc]);
    }
}

// K9: fused lin2 + sigmoid + bilinear-upsample + LUT interp + weighted sum + clip.
// Block = (bb,c) x 8 rows. Per block: lin2 -> swl[9][64]; y-interps for the 8
// rows -> su8[8][72]; then a barrier-free row loop.
__global__ __launch_bounds__(256) void k_apply(const float* __restrict__ img,
                                               const float* __restrict__ h1,
                                               const float* __restrict__ l2w,
                                               const float* __restrict__ l2b,
                                               const float* __restrict__ luts,
                                               float* __restrict__ out) {
    __shared__ float2 slut2[9 * 256];
    __shared__ float swl[9 * 64];
    __shared__ float su8[8 * 72];
    const int tid = threadIdx.x;
    const int bc = blockIdx.y;  // 0..5
    const int bb = bc / 3, c = bc % 3;

    for (int i = tid; i < 9 * 256; i += 256) {
        int k = i >> 8, j = i & 255;
        const float* lp = luts + (size_t)(c * 9 + k) * 256;
        float v0 = lp[j];
        float v1 = lp[j < 255 ? j + 1 : 255];
        slut2[i] = make_float2(v0, v1);
    }
    // lin2 (9 ocs for this c) + sigmoid, h1 read straight from global (L2-hot)
    {
        const float* hp = h1 + (size_t)bb * 128 * 64;
        const int pix = tid & 63;
        for (int o = tid >> 6; o < 9; o += 4) {
            const float* wp = l2w + (size_t)(c * 9 + o) * 128;
            float s = l2b[c * 9 + o];
            for (int ic = 0; ic < 128; ++ic) s = fmaf(hp[ic * 64 + pix], wp[ic], s);
            swl[o * 64 + pix] = sigmoid_f(s);
        }
    }
    __syncthreads();
    // y-interp for this block's 8 rows: su8[rr][k*8+x]
    for (int i = tid; i < 576; i += 256) {
        int rr = i / 72, rem = i % 72;
        int k = rem >> 3, xx = rem & 7;
        int h = blockIdx.x * 8 + rr;
        float py = h * (7.f / 1023.f);
        int iy0 = (int)py; if (iy0 > 6) iy0 = 6;
        float fy = py - (float)iy0;
        float a = swl[k * 64 + iy0 * 8 + xx];
        float b = swl[k * 64 + iy0 * 8 + 8 + xx];
        su8[i] = fmaf(fy, b - a, a);
    }
    __syncthreads();

    const int x0 = tid * 4;
    float fx[4]; int sel[4]; int cbase;
    {
        float p0 = x0 * (7.f / 1023.f);
        int ib = (int)p0; if (ib > 6) ib = 6;
        cbase = ib;
#pragma unroll
        for (int p = 0; p < 4; ++p) {
            float pxf = (x0 + p) * (7.f / 1023.f);
            int i = (int)pxf; if (i > 6) i = 6;
            sel[p] = i - cbase;          // 0 or 1
            fx[p] = pxf - (float)i;
        }
    }
    const size_t plane = ((size_t)bb * 3 + c) * 1024;

    for (int rr = 0; rr < 8; ++rr) {
        const int h = blockIdx.x * 8 + rr;
        const size_t base = (plane + h) * 1024;
        float4 v = ((const float4*)(img + base))[tid];
        float xin[4] = {v.x, v.y, v.z, v.w};
        int i0[4]; float fr[4]; float acc[4] = {0.f, 0.f, 0.f, 0.f};
#pragma unroll
        for (int p = 0; p < 4; ++p) {
            float pv = fminf(fmaxf(xin[p], 0.f), 1.f) * 255.f;
            int i = (int)pv; if (i > 254) i = 254;
            i0[p] = i; fr[p] = pv - (float)i;
        }
        const float* srow = su8 + rr * 72;
#pragma unroll
        for (int k = 0; k < 9; ++k) {
            float s0 = srow[k * 8 + cbase];
            float s1 = srow[k * 8 + cbase + 1];                    // cbase <= 6
            float s2 = (cbase < 6) ? srow[k * 8 + cbase + 2] : s1; // guard OOB; unused if cbase==6
            const float2* lrow = slut2 + k * 256;
#pragma unroll
            for (int p = 0; p < 4; ++p) {
                float a = sel[p] ? s1 : s0;
                float b = sel[p] ? s2 : s1;
                float wt = fmaf(fx[p], b - a, a);
                float2 l = lrow[i0[p]];
                acc[p] = fmaf(wt, fmaf(fr[p], l.y - l.x, l.x), acc[p]);
            }
        }
        float4 o4 = make_float4(fminf(fmaxf(acc[0], 0.f), 1.f),
                                fminf(fmaxf(acc[1], 0.f), 1.f),
                                fminf(fmaxf(acc[2], 0.f), 1.f),
                                fminf(fmaxf(acc[3], 0.f), 1.f));
        ((float4*)(out + base))[tid] = o4;
    }
}

extern "C" void kernel_launch(void* const* d_in, const int* in_sizes, int n_in,
                              void* d_out, int out_size, void* d_ws, size_t ws_size,
                              hipStream_t stream) {
    const float* img     = (const float*)d_in[0];
    const float* conv1_w = (const float*)d_in[1];
    const float* conv1_b = (const float*)d_in[2];
    const float* conv2_w = (const float*)d_in[3];
    const float* conv2_b = (const float*)d_in[4];
    const float* conv3_w = (const float*)d_in[5];
    const float* conv3_b = (const float*)d_in[6];
    const float* conv4_w = (const float*)d_in[7];
    const float* conv4_b = (const float*)d_in[8];
    const float* lin1_w  = (const float*)d_in[9];
    const float* lin1_b  = (const float*)d_in[10];
    const float* lin2_w  = (const float*)d_in[11];
    const float* lin2_b  = (const float*)d_in[12];
    const float* luts    = (const float*)d_in[13];
    float* out = (float*)d_out;

    float* ws = (float*)d_ws;
    float* x_rs = ws;            ws += 2 * 3 * 256 * 256;
    float* c1   = ws;            ws += 2 * 32 * 128 * 128;
    float* c2   = ws;            ws += 2 * 64 * 64 * 64;
    float* c3   = ws;            ws += 2 * 128 * 32 * 32;
    float* c4   = ws;            ws += 2 * 256 * 16 * 16;
    float* feat = ws;            ws += 2 * 480 * 8 * 8;
    float* h1   = ws;            ws += 2 * 128 * 8 * 8;

    const int B = 256;
    k_resize<<<6 * 256, B, 0, stream>>>(img, x_rs);
    // conv1: 512 px-blocks * 4 oc-octets = 2048
    k_conv_woc<3, 256, 256, 32><<<2048, B, 0, stream>>>(x_rs, conv1_w, conv1_b, c1);
    // conv2: 128 px-blocks * 8 oc-octets = 1024
    k_conv_woc<32, 128, 128, 64><<<1024, B, 0, stream>>>(c1, conv2_w, conv2_b, c2);
    // conv3: wave-split KC4, OC2 -> 32 * 64 = 2048 blocks
    k_conv_w4<64, 64, 64, 128, 2><<<2048, B, 0, stream>>>(c2, conv3_w, conv3_b, c3);
    // conv4: wave-split KC4, OC2 -> 8 * 128 = 1024 blocks
    k_conv_w4<128, 32, 32, 256, 2><<<1024, B, 0, stream>>>(c3, conv4_w, conv4_b, c4);
    k_pool<<<(2 * 480 * 64 + B - 1) / B, B, 0, stream>>>(c1, c2, c3, c4, feat);
    k_lin1<<<256, 512, 0, stream>>>(feat, lin1_w, lin1_b, h1);
    dim3 agrid(128, 6);
    k_apply<<<agrid, B, 0, stream>>>(img, h1, lin2_w, lin2_b, luts, out);
}